// Round 2
// baseline (678.680 us; speedup 1.0000x reference)
//
#include <hip/hip_runtime.h>
#include <math.h>

// Problem constants: B=2, S=2048, D=512, H=8, DH=64, HID=2048, tokens M=4096.
#define S_ 2048
#define D_ 512
#define H_ 8
#define DH_ 64
#define HID_ 2048
#define NT_ 4096          // B*S tokens
#define K3D_ 1536         // 3*D

typedef unsigned short u16;
typedef __bf16 bf16x8 __attribute__((ext_vector_type(8)));
typedef float f32x4 __attribute__((ext_vector_type(4)));

typedef const __attribute__((address_space(1))) unsigned int* gas_p;
typedef __attribute__((address_space(3))) unsigned int* las_p;

__device__ __forceinline__ float b2f(u16 u) {
  union { unsigned int i; float f; } v; v.i = ((unsigned int)u) << 16; return v.f;
}
__device__ __forceinline__ u16 f2b(float f) {
  union { float f; unsigned int i; } v; v.f = f;
  unsigned int u = v.i;
  u += 0x7fffu + ((u >> 16) & 1u);   // RN-even; inputs finite
  return (u16)(u >> 16);
}

// ---------------------------------------------------------------------------
// fp32 -> bf16 elementwise convert (8 elems/thread)
// ---------------------------------------------------------------------------
__global__ __launch_bounds__(256) void cvt_kernel(
    const float* __restrict__ in, u16* __restrict__ out, int n8) {
  int i = blockIdx.x * 256 + threadIdx.x;
  if (i >= n8) return;
  size_t base = (size_t)i * 8;
  float4 a = *(const float4*)(in + base);
  float4 b = *(const float4*)(in + base + 4);
  u16 ov[8] = {f2b(a.x), f2b(a.y), f2b(a.z), f2b(a.w),
               f2b(b.x), f2b(b.y), f2b(b.z), f2b(b.w)};
  *(uint4*)(out + base) = *(uint4*)ov;
}

// ---------------------------------------------------------------------------
// Transpose+convert: in fp32 [R,C] row-major -> out bf16 [C,R] row-major
// ---------------------------------------------------------------------------
__global__ __launch_bounds__(256) void transpose_kernel(
    const float* __restrict__ in, u16* __restrict__ out, int R, int C) {
  int idx = blockIdx.x * 256 + threadIdx.x;
  if (idx >= R * C) return;
  int r = idx / C, c = idx % C;
  out[(size_t)c * R + r] = f2b(in[idx]);
}

// V chunk of kqv (bf16) -> Vt[bh][dh=64][key=2048] (bf16)
__global__ __launch_bounds__(256) void vt_kernel(
    const u16* __restrict__ kqv, u16* __restrict__ vt) {
  int bh = blockIdx.y, b = bh >> 3, h = bh & 7;
  const u16* V = kqv + (size_t)b * S_ * K3D_ + 2 * D_ + h * DH_;
  u16* O = vt + (size_t)bh * DH_ * S_;
  int idx = blockIdx.x * 256 + threadIdx.x;   // over 2048*64
  int r = idx >> 6, c = idx & 63;             // r = key token, c = dh
  O[(size_t)c * S_ + r] = V[(size_t)r * K3D_ + c];
}

// ---------------------------------------------------------------------------
// MFMA GEMM (m97 structure): C[M,N] = epi(A[M,K] @ Bt[N,K]^T); A,Bt bf16.
// BM=128, BN template (128 or 64), BK=32. 256 threads = 4 waves in 2x2.
// global_load_lds width-16 direct staging into LINEAR (unpadded) LDS
// [rows][32] (64B rows) -- dest is wave-uniform base + lane*16, so LDS must
// be contiguous in lane order; padding would break it.
// Per K-step per wave: 4+NF ds_read_b128, 4*NF MFMA, 2 barriers.
// gelu=1: exact GELU epilogue.
// ---------------------------------------------------------------------------
template<int BN>
__global__ __launch_bounds__(256) void gemm_glds(
    const u16* __restrict__ A, const u16* __restrict__ Bt,
    const float* __restrict__ bias, u16* __restrict__ C,
    int K, int lda, int ldb, int ldc, int gelu) {
  constexpr int BM = 128;
  constexpr int NF = BN / 32;                 // n-frags per wave
  constexpr int A_LOADS = BM / 64;            // 1KB wave-loads per wave (A)
  constexpr int B_LOADS = BN / 64;            //   "         "        (B)

  __shared__ alignas(16) u16 As[BM * 32];     // linear, 64B rows
  __shared__ alignas(16) u16 Bs[BN * 32];

  int t = threadIdx.x;
  int w = t >> 6, lane = t & 63, quad = lane >> 4, l16 = lane & 15;
  int wr = w >> 1, wc = w & 1;                // wave 2x2 grid
  int tile_m = blockIdx.y * BM, tile_n = blockIdx.x * BN;

  int srow = lane >> 2, schunk = (lane & 3) * 8;   // lane -> 16B chunk

  f32x4 acc[4][NF];
#pragma unroll
  for (int i = 0; i < 4; ++i)
#pragma unroll
    for (int n = 0; n < NF; ++n) acc[i][n] = (f32x4){0.f, 0.f, 0.f, 0.f};

  for (int kb = 0; kb < K; kb += 32) {
    __syncthreads();                      // prior ds_reads done before overwrite
#pragma unroll
    for (int j = 0; j < A_LOADS; ++j) {
      int jj = w * A_LOADS + j;           // 1KB block index (16 rows)
      const u16* g = A + (size_t)(tile_m + jj * 16 + srow) * lda + kb + schunk;
      __builtin_amdgcn_global_load_lds((gas_p)(const void*)g,
                                       (las_p)(void*)(As + jj * 512), 16, 0, 0);
    }
#pragma unroll
    for (int j = 0; j < B_LOADS; ++j) {
      int jj = w * B_LOADS + j;
      const u16* g = Bt + (size_t)(tile_n + jj * 16 + srow) * ldb + kb + schunk;
      __builtin_amdgcn_global_load_lds((gas_p)(const void*)g,
                                       (las_p)(void*)(Bs + jj * 512), 16, 0, 0);
    }
    __syncthreads();                      // drains vmcnt -> tiles visible

    bf16x8 af[4], bfr[NF];
#pragma unroll
    for (int i = 0; i < 4; ++i)
      af[i] = *(const bf16x8*)(&As[(wr * 64 + i * 16 + l16) * 32 + quad * 8]);
#pragma unroll
    for (int n = 0; n < NF; ++n)
      bfr[n] = *(const bf16x8*)(&Bs[(wc * (BN / 2) + n * 16 + l16) * 32 + quad * 8]);
#pragma unroll
    for (int i = 0; i < 4; ++i)
#pragma unroll
      for (int n = 0; n < NF; ++n)
        acc[i][n] = __builtin_amdgcn_mfma_f32_16x16x32_bf16(af[i], bfr[n], acc[i][n], 0, 0, 0);
  }

#pragma unroll
  for (int n = 0; n < NF; ++n) {
    int col = tile_n + wc * (BN / 2) + n * 16 + l16;
    float bcol = bias[col];
#pragma unroll
    for (int i = 0; i < 4; ++i) {
#pragma unroll
      for (int r = 0; r < 4; ++r) {
        int row = tile_m + wr * 64 + i * 16 + quad * 4 + r;
        float v = acc[i][n][r] + bcol;
        if (gelu) v = 0.5f * v * (1.f + erff(v * 0.70710678118654752f));
        C[(size_t)row * ldc + col] = f2b(v);
      }
    }
  }
}

// ---------------------------------------------------------------------------
// Fused flash attention with energy side-output.
// Grid (S/64, B*H); block 256 = 4 waves; wave w owns q-rows [qbase+16w, +16).
// Per 64-key tile: S = Q@K^T (MFMA) -> LDS transpose -> coalesced float4
// prev-read + energy-write -> online softmax (m,l,rescale in LDS) ->
// P(bf16)->LDS->MFMA P@V with O-rescale. K/V double-buffered in LDS,
// issue-early/write-late staging, ONE __syncthreads per k-tile.
// Es/Pt/stats are wave-private: per-wave LDS ops execute in order in HW;
// asm memory fences stop compiler reordering without draining vmcnt.
// ---------------------------------------------------------------------------
__global__ __launch_bounds__(256) void fused_attn(
    const u16* __restrict__ kqv, const u16* __restrict__ vt,
    const float* __restrict__ prev, float* __restrict__ energy,
    u16* __restrict__ ctx) {
  int bh = blockIdx.y, b = bh >> 3, h = bh & 7;
  int qbase = blockIdx.x * 64;

  const u16* Qp  = kqv + (size_t)b * S_ * K3D_ + D_ + h * DH_;   // k,q,v order
  const u16* Kp  = kqv + (size_t)b * S_ * K3D_ + h * DH_;
  const u16* Vtp = vt + (size_t)bh * DH_ * S_;
  const float* Pvp = prev + (size_t)bh * S_ * S_;
  float* Ep = energy + (size_t)bh * S_ * S_;

  int t = threadIdx.x;
  int w = t >> 6, lane = t & 63, quad = lane >> 4, l16 = lane & 15;

  __shared__ alignas(16) u16 KsB[2][64 * 72];   // [key][dh], pad 64->72
  __shared__ alignas(16) u16 VsB[2][64 * 72];   // [dh][key], pad 64->72
  __shared__ alignas(16) float Es[4][16 * 68];  // per-wave S rows (f32)
  __shared__ alignas(16) u16 Pt[4][16 * 72];    // per-wave P rows (bf16)
  __shared__ float m_s[4][16];
  __shared__ float l_s[4][16];
  __shared__ float r_s[4][16];

  // Q fragments (A-operand: row=l16, k=quad*8), K=64 -> 2 chunks of 32
  bf16x8 qf0, qf1;
  {
    const u16* qrow = Qp + (size_t)(qbase + w * 16 + l16) * K3D_;
    qf0 = *(const bf16x8*)(qrow + quad * 8);
    qf1 = *(const bf16x8*)(qrow + 32 + quad * 8);
  }

  if (lane < 16) { m_s[w][lane] = -1e30f; l_s[w][lane] = 0.f; }

  f32x4 oa[4];
#pragma unroll
  for (int i = 0; i < 4; ++i) oa[i] = (f32x4){0.f, 0.f, 0.f, 0.f};

  // staging: 512 chunks of 16B (64 rows x 128B); 2 chunks/thread
  int c0 = t * 2, c1 = c0 + 1;
  int kr0 = c0 >> 3, ko0 = (c0 & 7) * 8;
  int kr1 = c1 >> 3, ko1 = (c1 & 7) * 8;

  { // prologue: stage tile 0 into buf 0
    uint4 ka0 = *(const uint4*)(Kp + (size_t)kr0 * K3D_ + ko0);
    uint4 ka1 = *(const uint4*)(Kp + (size_t)kr1 * K3D_ + ko1);
    uint4 va0 = *(const uint4*)(Vtp + (size_t)kr0 * S_ + ko0);
    uint4 va1 = *(const uint4*)(Vtp + (size_t)kr1 * S_ + ko1);
    *(uint4*)(&KsB[0][kr0 * 72 + ko0]) = ka0;
    *(uint4*)(&KsB[0][kr1 * 72 + ko1]) = ka1;
    *(uint4*)(&VsB[0][kr0 * 72 + ko0]) = va0;
    *(uint4*)(&VsB[0][kr1 * 72 + ko1]) = va1;
  }
  __syncthreads();

  for (int it = 0; it < 32; ++it) {
    int cur = it & 1;
    int kb = it * 64;

    // issue next tile's global loads early (latency hides under compute)
    uint4 ka0, ka1, va0, va1;
    if (it < 31) {
      int kn = kb + 64;
      ka0 = *(const uint4*)(Kp + (size_t)(kn + kr0) * K3D_ + ko0);
      ka1 = *(const uint4*)(Kp + (size_t)(kn + kr1) * K3D_ + ko1);
      va0 = *(const uint4*)(Vtp + (size_t)kr0 * S_ + kn + ko0);
      va1 = *(const uint4*)(Vtp + (size_t)kr1 * S_ + kn + ko1);
    }

    const u16* Ks = KsB[cur];
    const u16* Vs = VsB[cur];

    // ---- S = Q @ K^T ----
    f32x4 sa[4];
#pragma unroll
    for (int i = 0; i < 4; ++i) sa[i] = (f32x4){0.f, 0.f, 0.f, 0.f};
#pragma unroll
    for (int kc = 0; kc < 2; ++kc) {
      bf16x8 a = kc ? qf1 : qf0;
#pragma unroll
      for (int nt = 0; nt < 4; ++nt) {
        bf16x8 bk = *(const bf16x8*)(&Ks[(nt * 16 + l16) * 72 + kc * 32 + quad * 8]);
        sa[nt] = __builtin_amdgcn_mfma_f32_16x16x32_bf16(a, bk, sa[nt], 0, 0, 0);
      }
    }

    // ---- fragment -> row-major LDS (scale folded) ----
#pragma unroll
    for (int nt = 0; nt < 4; ++nt)
#pragma unroll
      for (int r = 0; r < 4; ++r)
        Es[w][(quad * 4 + r) * 68 + nt * 16 + l16] = sa[nt][r] * 0.125f;
    asm volatile("" ::: "memory");

    // ---- pass A: e = S + prev; coalesced energy write; row max ----
    float4 ek[4];
    float mt[4];
#pragma unroll
    for (int r4 = 0; r4 < 4; ++r4) {
      int row = r4 * 4 + quad;
      float4 e4 = *(const float4*)(&Es[w][row * 68 + l16 * 4]);
      size_t goff = (size_t)(qbase + w * 16 + row) * S_ + kb + l16 * 4;
      float4 p4 = *(const float4*)(Pvp + goff);
      e4.x += p4.x; e4.y += p4.y; e4.z += p4.z; e4.w += p4.w;
      *(float4*)(Ep + goff) = e4;
      ek[r4] = e4;
      mt[r4] = fmaxf(fmaxf(e4.x, e4.y), fmaxf(e4.z, e4.w));
    }
#pragma unroll
    for (int r4 = 0; r4 < 4; ++r4)
#pragma unroll
      for (int off = 1; off < 16; off <<= 1)
        mt[r4] = fmaxf(mt[r4], __shfl_xor(mt[r4], off, 16));
    if (l16 == 0) {
#pragma unroll
      for (int r4 = 0; r4 < 4; ++r4) {
        int row = r4 * 4 + quad;
        float mo = m_s[w][row];
        float mn = fmaxf(mo, mt[r4]);
        r_s[w][row] = __expf(mo - mn);
        m_s[w][row] = mn;
      }
    }
    asm volatile("" ::: "memory");

    // ---- pass B: P = exp(e - m_new) -> Pt(bf16); l update; O rescale ----
    float ls[4];
#pragma unroll
    for (int r4 = 0; r4 < 4; ++r4) {
      int row = r4 * 4 + quad;
      float mrow = m_s[w][row];
      float4 e4 = ek[r4];
      float p0 = __expf(e4.x - mrow), p1 = __expf(e4.y - mrow);
      float p2 = __expf(e4.z - mrow), p3 = __expf(e4.w - mrow);
      ls[r4] = (p0 + p1) + (p2 + p3);
      u16 pb[4] = {f2b(p0), f2b(p1), f2b(p2), f2b(p3)};
      *(uint2*)(&Pt[w][row * 72 + l16 * 4]) = *(uint2*)pb;
    }
#pragma unroll
    for (int r4 = 0; r4 < 4; ++r4)
#pragma unroll
      for (int off = 1; off < 16; off <<= 1)
        ls[r4] += __shfl_xor(ls[r4], off, 16);
    if (l16 == 0) {
#pragma unroll
      for (int r4 = 0; r4 < 4; ++r4) {
        int row = r4 * 4 + quad;
        l_s[w][row] = l_s[w][row] * r_s[w][row] + ls[r4];
      }
    }
#pragma unroll
    for (int rr = 0; rr < 4; ++rr) {
      float rf = r_s[w][quad * 4 + rr];
#pragma unroll
      for (int nt = 0; nt < 4; ++nt) oa[nt][rr] *= rf;
    }
    asm volatile("" ::: "memory");

    // ---- O += P @ V ----
#pragma unroll
    for (int kc = 0; kc < 2; ++kc) {
      bf16x8 a = *(const bf16x8*)(&Pt[w][l16 * 72 + kc * 32 + quad * 8]);
#pragma unroll
      for (int nt = 0; nt < 4; ++nt) {
        bf16x8 bv = *(const bf16x8*)(&Vs[(nt * 16 + l16) * 72 + kc * 32 + quad * 8]);
        oa[nt] = __builtin_amdgcn_mfma_f32_16x16x32_bf16(a, bv, oa[nt], 0, 0, 0);
      }
    }

    // ---- write-late staging into the other buffer; single barrier ----
    if (it < 31) {
      int nxt = cur ^ 1;
      *(uint4*)(&KsB[nxt][kr0 * 72 + ko0]) = ka0;
      *(uint4*)(&KsB[nxt][kr1 * 72 + ko1]) = ka1;
      *(uint4*)(&VsB[nxt][kr0 * 72 + ko0]) = va0;
      *(uint4*)(&VsB[nxt][kr1 * 72 + ko1]) = va1;
      __syncthreads();
    }
  }

  asm volatile("" ::: "memory");
  // epilogue: O / l -> ctx bf16
  float il[4];
#pragma unroll
  for (int rr = 0; rr < 4; ++rr) il[rr] = 1.f / l_s[w][quad * 4 + rr];
#pragma unroll
  for (int nt = 0; nt < 4; ++nt) {
    int col = h * DH_ + nt * 16 + l16;
#pragma unroll
    for (int rr = 0; rr < 4; ++rr) {
      size_t row = (size_t)b * S_ + qbase + w * 16 + quad * 4 + rr;
      ctx[row * D_ + col] = f2b(oa[nt][rr] * il[rr]);
    }
  }
}

// ---------------------------------------------------------------------------
// LayerNorm: o = LN(a + r) * g + be. a bf16; r fp32 or bf16; o fp32 or bf16.
// One wave per 512-elem row, 4 rows/WG.
// ---------------------------------------------------------------------------
__global__ __launch_bounds__(256) void ln_kernel(
    const u16* __restrict__ a, const void* __restrict__ rsrc,
    const float* __restrict__ g, const float* __restrict__ be,
    void* __restrict__ o, int r_f32, int o_f32) {
  int row = blockIdx.x * 4 + (threadIdx.x >> 6);
  int lane = threadIdx.x & 63;
  size_t base = (size_t)row * D_ + lane * 8;
  uint4 av = *(const uint4*)(a + base);
  const u16* ap = (const u16*)&av;
  float rv[8];
  if (r_f32) {
    float4 r0 = *(const float4*)((const float*)rsrc + base);
    float4 r1 = *(const float4*)((const float*)rsrc + base + 4);
    rv[0] = r0.x; rv[1] = r0.y; rv[2] = r0.z; rv[3] = r0.w;
    rv[4] = r1.x; rv[5] = r1.y; rv[6] = r1.z; rv[7] = r1.w;
  } else {
    uint4 rr = *(const uint4*)((const u16*)rsrc + base);
    const u16* rp = (const u16*)&rr;
#pragma unroll
    for (int j = 0; j < 8; ++j) rv[j] = b2f(rp[j]);
  }
  float tv[8], s = 0.f, sq = 0.f;
#pragma unroll
  for (int j = 0; j < 8; ++j) {
    float xx = b2f(ap[j]) + rv[j];
    tv[j] = xx; s += xx; sq += xx * xx;
  }
#pragma unroll
  for (int off = 32; off; off >>= 1) {
    s  += __shfl_xor(s, off);
    sq += __shfl_xor(sq, off);
  }
  float mu  = s * (1.f / 512.f);
  float var = fmaxf(sq * (1.f / 512.f) - mu * mu, 0.f);
  float wv  = rsqrtf(var + 1e-5f);
  float4 g0 = *(const float4*)(g + lane * 8);
  float4 g1 = *(const float4*)(g + lane * 8 + 4);
  float4 b0 = *(const float4*)(be + lane * 8);
  float4 b1 = *(const float4*)(be + lane * 8 + 4);
  float gv[8] = {g0.x, g0.y, g0.z, g0.w, g1.x, g1.y, g1.z, g1.w};
  float bv[8] = {b0.x, b0.y, b0.z, b0.w, b1.x, b1.y, b1.z, b1.w};
  if (o_f32) {
    float ov[8];
#pragma unroll
    for (int j = 0; j < 8; ++j) ov[j] = (tv[j] - mu) * wv * gv[j] + bv[j];
    *(float4*)((float*)o + base)     = *(float4*)(ov);
    *(float4*)((float*)o + base + 4) = *(float4*)(ov + 4);
  } else {
    u16 ov[8];
#pragma unroll
    for (int j = 0; j < 8; ++j) ov[j] = f2b((tv[j] - mu) * wv * gv[j] + bv[j]);
    *(uint4*)((u16*)o + base) = *(uint4*)ov;
  }
}

// ---------------------------------------------------------------------------
// Workspace plan (29.5 MiB, lifetime-aliased; u16 element offsets):
//   R0 [8,388,608]: kqv (steps 2-5) ; vt in tail [6,291,456..) (3-4) ;
//                   attn in head [0..2,097,152) (6-7) ; ff whole (8-9)
//   R2 [2,097,152]: ctx (4-6) then f2 (9-10)
//   R3 [2,097,152]: hbuf (7-10)
//   R4 [2,097,152]: xb (1-2) then fc1_wt [0..1,048,576) + fc2_wt [1,048,576..)
//   WA [786,432]:   kqv_wt (->2) then out_wt (->6)
// ---------------------------------------------------------------------------
extern "C" void kernel_launch(void* const* d_in, const int* in_sizes, int n_in,
                              void* d_out, int out_size, void* d_ws, size_t ws_size,
                              hipStream_t stream) {
  const float* x     = (const float*)d_in[0];
  const float* prev  = (const float*)d_in[1];
  const float* kqv_w = (const float*)d_in[2];
  const float* kqv_b = (const float*)d_in[3];
  const float* out_w = (const float*)d_in[4];
  const float* out_b = (const float*)d_in[5];
  const float* fc1_w = (const float*)d_in[6];
  const float* fc1_b = (const float*)d_in[7];
  const float* fc2_w = (const float*)d_in[8];
  const float* fc2_b = (const float*)d_in[9];
  const float* ln1_g = (const float*)d_in[10];
  const float* ln1_b = (const float*)d_in[11];
  const float* ln2_g = (const float*)d_in[12];
  const float* ln2_b = (const float*)d_in[13];

  float* outp   = (float*)d_out;                    // [4096,512] fp32
  float* energy = outp + (size_t)NT_ * D_;          // [16,2048,2048] fp32

  u16* ws = (u16*)d_ws;
  u16* R0 = ws;                       // 8,388,608
  u16* R2 = R0 + (size_t)8388608;     // 2,097,152
  u16* R3 = R2 + (size_t)2097152;     // 2,097,152
  u16* R4 = R3 + (size_t)2097152;     // 2,097,152
  u16* WA = R4 + (size_t)2097152;     // 786,432   (total 15,466,496 u16 = 29.5 MiB)

  u16* kqv    = R0;
  u16* vt     = R0 + (size_t)6291456;
  u16* attn   = R0;
  u16* ff     = R0;
  u16* ctx    = R2;  u16* f2     = R2;
  u16* hbuf   = R3;
  u16* xb     = R4;
  u16* fc1_wt = R4;  u16* fc2_wt = R4 + (size_t)1048576;
  u16* kqv_wt = WA;  u16* out_wt = WA;

  // step 1: xb = bf16(x); kqv_wt
  cvt_kernel<<<(NT_ * D_ / 8 + 255) / 256, 256, 0, stream>>>(x, xb, NT_ * D_ / 8);
  transpose_kernel<<<(D_ * K3D_ + 255) / 256, 256, 0, stream>>>(kqv_w, kqv_wt, D_, K3D_);

  // step 2: kqv = xb @ kqv_w + b : M=4096 N=1536 K=512
  gemm_glds<128><<<dim3(K3D_ / 128, NT_ / 128, 1), 256, 0, stream>>>(
      xb, kqv_wt, kqv_b, kqv, D_, D_, D_, K3D_, 0);

  // step 1b: remaining weight transposes (xb, kqv_wt now dead)
  transpose_kernel<<<(D_ * HID_ + 255) / 256, 256, 0, stream>>>(fc1_w, fc1_wt, D_, HID_);
  transpose_kernel<<<(HID_ * D_ + 255) / 256, 256, 0, stream>>>(fc2_w, fc2_wt, HID_, D_);
  transpose_kernel<<<(D_ * D_ + 255) / 256, 256, 0, stream>>>(out_w, out_wt, D_, D_);

  // step 3: Vt for PV MFMA
  vt_kernel<<<dim3((S_ * DH_) / 256, 16), 256, 0, stream>>>(kqv, vt);

  // step 4: fused flash attention: energy out (fp32) + ctx (bf16)
  fused_attn<<<dim3(S_ / 64, 16), 256, 0, stream>>>(kqv, vt, prev, energy, ctx);

  // step 6: attn = ctx @ out_w + b  (bf16, into R0 head); BN=64 -> 256 blocks
  gemm_glds<64><<<dim3(D_ / 64, NT_ / 128, 1), 256, 0, stream>>>(
      ctx, out_wt, out_b, attn, D_, D_, D_, D_, 0);

  // step 7: h = LN1(attn + x)  -> hbuf bf16   (r fp32, o bf16)
  ln_kernel<<<NT_ / 4, 256, 0, stream>>>(attn, x, ln1_g, ln1_b, hbuf, 1, 0);

  // step 8: ff = gelu(h @ fc1_w + b)  (writes all R0; attn/vt dead)
  gemm_glds<128><<<dim3(HID_ / 128, NT_ / 128, 1), 256, 0, stream>>>(
      hbuf, fc1_wt, fc1_b, ff, D_, D_, D_, HID_, 1);

  // step 9: f2 = ff @ fc2_w + b  (writes R2; ctx dead); BN=64 -> 256 blocks
  gemm_glds<64><<<dim3(D_ / 64, NT_ / 128, 1), 256, 0, stream>>>(
      ff, fc2_wt, fc2_b, f2, HID_, HID_, HID_, D_, 0);

  // step 10: out = LN2(f2 + h) -> fp32  (r bf16, o fp32)
  ln_kernel<<<NT_ / 4, 256, 0, stream>>>(f2, hbuf, ln2_g, ln2_b, outp, 0, 1);
}

// Round 3
// 633.590 us; speedup vs baseline: 1.0712x; 1.0712x over previous
//
#include <hip/hip_runtime.h>
#include <math.h>

// Problem constants: B=2, S=2048, D=512, H=8, DH=64, HID=2048, tokens M=4096.
#define S_ 2048
#define D_ 512
#define H_ 8
#define DH_ 64
#define HID_ 2048
#define NT_ 4096          // B*S tokens
#define K3D_ 1536         // 3*D

typedef unsigned short u16;
typedef __bf16 bf16x8 __attribute__((ext_vector_type(8)));
typedef float f32x4 __attribute__((ext_vector_type(4)));

typedef const __attribute__((address_space(1))) unsigned int* gas_p;
typedef __attribute__((address_space(3))) unsigned int* las_p;

__device__ __forceinline__ float b2f(u16 u) {
  union { unsigned int i; float f; } v; v.i = ((unsigned int)u) << 16; return v.f;
}
__device__ __forceinline__ u16 f2b(float f) {
  union { float f; unsigned int i; } v; v.f = f;
  unsigned int u = v.i;
  u += 0x7fffu + ((u >> 16) & 1u);   // RN-even; inputs finite
  return (u16)(u >> 16);
}

// ---------------------------------------------------------------------------
// fp32 -> bf16 elementwise convert (8 elems/thread)
// ---------------------------------------------------------------------------
__global__ __launch_bounds__(256) void cvt_kernel(
    const float* __restrict__ in, u16* __restrict__ out, int n8) {
  int i = blockIdx.x * 256 + threadIdx.x;
  if (i >= n8) return;
  size_t base = (size_t)i * 8;
  float4 a = *(const float4*)(in + base);
  float4 b = *(const float4*)(in + base + 4);
  u16 ov[8] = {f2b(a.x), f2b(a.y), f2b(a.z), f2b(a.w),
               f2b(b.x), f2b(b.y), f2b(b.z), f2b(b.w)};
  *(uint4*)(out + base) = *(uint4*)ov;
}

// ---------------------------------------------------------------------------
// Tiled transpose+convert: in fp32 [R,C] row-major -> out bf16 [C,R].
// 32x32 LDS tile; coalesced float4 reads, coalesced 8B writes.
// Grid (C/32, R/32); R,C multiples of 32.
// ---------------------------------------------------------------------------
__global__ __launch_bounds__(256) void transpose_t32(
    const float* __restrict__ in, u16* __restrict__ out, int R, int C) {
  __shared__ u16 tile[32][40];
  int r0 = blockIdx.y * 32, c0 = blockIdx.x * 32;
  int t = threadIdx.x;
  int r = t >> 3, c4 = (t & 7) * 4;
  float4 v = *(const float4*)(in + (size_t)(r0 + r) * C + c0 + c4);
  tile[r][c4 + 0] = f2b(v.x);
  tile[r][c4 + 1] = f2b(v.y);
  tile[r][c4 + 2] = f2b(v.z);
  tile[r][c4 + 3] = f2b(v.w);
  __syncthreads();
  int c = t >> 3, r4 = (t & 7) * 4;
  u16 o[4] = {tile[r4 + 0][c], tile[r4 + 1][c], tile[r4 + 2][c], tile[r4 + 3][c]};
  *(uint2*)(out + (size_t)(c0 + c) * R + r0 + r4) = *(uint2*)o;
}

// ---------------------------------------------------------------------------
// Tiled V transpose: kqv V chunk [key][dh] (stride K3D) -> vt[bh][dh][key].
// 64x64 LDS tile; coalesced 16B reads and 16B writes. Grid (S/64, 16).
// ---------------------------------------------------------------------------
__global__ __launch_bounds__(256) void vt_tiled(
    const u16* __restrict__ kqv, u16* __restrict__ vt) {
  int bh = blockIdx.y, b = bh >> 3, h = bh & 7;
  const u16* V = kqv + (size_t)b * S_ * K3D_ + 2 * D_ + h * DH_;
  u16* O = vt + (size_t)bh * DH_ * S_;
  __shared__ u16 tile[64][72];
  int k0 = blockIdx.x * 64;
  int t = threadIdx.x;
  int kr = t >> 2, ko = (t & 3) * 16;
  uint4 v0 = *(const uint4*)(V + (size_t)(k0 + kr) * K3D_ + ko);
  uint4 v1 = *(const uint4*)(V + (size_t)(k0 + kr) * K3D_ + ko + 8);
  *(uint4*)(&tile[kr][ko]) = v0;
  *(uint4*)(&tile[kr][ko + 8]) = v1;
  __syncthreads();
  int dh = t >> 2, kk = (t & 3) * 16;
  u16 o[16];
#pragma unroll
  for (int j = 0; j < 16; ++j) o[j] = tile[kk + j][dh];
  *(uint4*)(O + (size_t)dh * S_ + k0 + kk)     = ((uint4*)o)[0];
  *(uint4*)(O + (size_t)dh * S_ + k0 + kk + 8) = ((uint4*)o)[1];
}

// ---------------------------------------------------------------------------
// MFMA GEMM, 2-phase double-buffered pipeline (T3-minimum recipe):
//   prologue: STAGE(buf0, k=0); barrier;
//   iter s:   STAGE(buf^1, k=s+1) FIRST (loads fly during compute);
//             ds_read buf[cur] + MFMA; barrier (drains stage + ds reads).
// BM=128, BN template (128/64), BK=32. 256 thr = 4 waves in 2x2.
// global_load_lds width-16 into LINEAR LDS [rows][32] (64B rows).
// ---------------------------------------------------------------------------
template<int BN>
__global__ __launch_bounds__(256) void gemm_glds(
    const u16* __restrict__ A, const u16* __restrict__ Bt,
    const float* __restrict__ bias, u16* __restrict__ C,
    int K, int lda, int ldb, int ldc, int gelu) {
  constexpr int BM = 128;
  constexpr int NF = BN / 32;                 // n-frags per wave
  constexpr int A_LOADS = BM / 64;            // 1KB wave-loads per wave (A)
  constexpr int B_LOADS = BN / 64;

  __shared__ alignas(16) u16 As[2][BM * 32];  // linear, 64B rows
  __shared__ alignas(16) u16 Bs[2][BN * 32];

  int t = threadIdx.x;
  int w = t >> 6, lane = t & 63, quad = lane >> 4, l16 = lane & 15;
  int wr = w >> 1, wc = w & 1;                // wave 2x2 grid
  int tile_m = blockIdx.y * BM, tile_n = blockIdx.x * BN;
  int srow = lane >> 2, schunk = (lane & 3) * 8;   // lane -> 16B chunk

  f32x4 acc[4][NF];
#pragma unroll
  for (int i = 0; i < 4; ++i)
#pragma unroll
    for (int n = 0; n < NF; ++n) acc[i][n] = (f32x4){0.f, 0.f, 0.f, 0.f};

#define STAGE_TILE(buf, kb)                                                   \
  {                                                                           \
    _Pragma("unroll")                                                         \
    for (int j = 0; j < A_LOADS; ++j) {                                       \
      int jj = w * A_LOADS + j;                                               \
      const u16* g = A + (size_t)(tile_m + jj * 16 + srow) * lda + (kb) + schunk; \
      __builtin_amdgcn_global_load_lds((gas_p)(const void*)g,                 \
          (las_p)(void*)(&As[buf][jj * 512]), 16, 0, 0);                      \
    }                                                                         \
    _Pragma("unroll")                                                         \
    for (int j = 0; j < B_LOADS; ++j) {                                       \
      int jj = w * B_LOADS + j;                                               \
      const u16* g = Bt + (size_t)(tile_n + jj * 16 + srow) * ldb + (kb) + schunk; \
      __builtin_amdgcn_global_load_lds((gas_p)(const void*)g,                 \
          (las_p)(void*)(&Bs[buf][jj * 512]), 16, 0, 0);                      \
    }                                                                         \
  }

  STAGE_TILE(0, 0);
  __syncthreads();

  int nsteps = K >> 5;
  for (int s = 0; s < nsteps; ++s) {
    int cur = s & 1;
    if (s + 1 < nsteps) STAGE_TILE(cur ^ 1, (s + 1) * 32);

    bf16x8 af[4], bfr[NF];
#pragma unroll
    for (int i = 0; i < 4; ++i)
      af[i] = *(const bf16x8*)(&As[cur][(wr * 64 + i * 16 + l16) * 32 + quad * 8]);
#pragma unroll
    for (int n = 0; n < NF; ++n)
      bfr[n] = *(const bf16x8*)(&Bs[cur][(wc * (BN / 2) + n * 16 + l16) * 32 + quad * 8]);
#pragma unroll
    for (int i = 0; i < 4; ++i)
#pragma unroll
      for (int n = 0; n < NF; ++n)
        acc[i][n] = __builtin_amdgcn_mfma_f32_16x16x32_bf16(af[i], bfr[n], acc[i][n], 0, 0, 0);

    if (s + 1 < nsteps) __syncthreads();   // drains next-tile stage + ds reads
  }
#undef STAGE_TILE

#pragma unroll
  for (int n = 0; n < NF; ++n) {
    int col = tile_n + wc * (BN / 2) + n * 16 + l16;
    float bcol = bias[col];
#pragma unroll
    for (int i = 0; i < 4; ++i) {
#pragma unroll
      for (int r = 0; r < 4; ++r) {
        int row = tile_m + wr * 64 + i * 16 + quad * 4 + r;
        float v = acc[i][n][r] + bcol;
        if (gelu) v = 0.5f * v * (1.f + erff(v * 0.70710678118654752f));
        C[(size_t)row * ldc + col] = f2b(v);
      }
    }
  }
}

// ---------------------------------------------------------------------------
// Fused flash attention with energy side-output.
// Grid (S/64, B*H); block 256 = 4 waves; wave w owns q-rows [qbase+16w, +16).
// prev is PREFETCHED one k-tile ahead into registers (16 VGPR) -- the 268MB
// prev stream is the kernel's largest; loading it in-pass serialized a full
// HBM latency per tile. K/V staged issue-early/write-late, double-buffered.
// ---------------------------------------------------------------------------
__global__ __launch_bounds__(256) void fused_attn(
    const u16* __restrict__ kqv, const u16* __restrict__ vt,
    const float* __restrict__ prev, float* __restrict__ energy,
    u16* __restrict__ ctx) {
  int bh = blockIdx.y, b = bh >> 3, h = bh & 7;
  int qbase = blockIdx.x * 64;

  const u16* Qp  = kqv + (size_t)b * S_ * K3D_ + D_ + h * DH_;   // k,q,v order
  const u16* Kp  = kqv + (size_t)b * S_ * K3D_ + h * DH_;
  const u16* Vtp = vt + (size_t)bh * DH_ * S_;
  const float* Pvp = prev + (size_t)bh * S_ * S_;
  float* Ep = energy + (size_t)bh * S_ * S_;

  int t = threadIdx.x;
  int w = t >> 6, lane = t & 63, quad = lane >> 4, l16 = lane & 15;

  __shared__ alignas(16) u16 KsB[2][64 * 72];   // [key][dh], pad 64->72
  __shared__ alignas(16) u16 VsB[2][64 * 72];   // [dh][key], pad 64->72
  __shared__ alignas(16) float Es[4][16 * 68];  // per-wave S rows (f32)
  __shared__ alignas(16) u16 Pt[4][16 * 72];    // per-wave P rows (bf16)
  __shared__ float m_s[4][16];
  __shared__ float l_s[4][16];
  __shared__ float r_s[4][16];

  // Q fragments (A-operand: row=l16, k=quad*8), K=64 -> 2 chunks of 32
  bf16x8 qf0, qf1;
  {
    const u16* qrow = Qp + (size_t)(qbase + w * 16 + l16) * K3D_;
    qf0 = *(const bf16x8*)(qrow + quad * 8);
    qf1 = *(const bf16x8*)(qrow + 32 + quad * 8);
  }

  if (lane < 16) { m_s[w][lane] = -1e30f; l_s[w][lane] = 0.f; }

  f32x4 oa[4];
#pragma unroll
  for (int i = 0; i < 4; ++i) oa[i] = (f32x4){0.f, 0.f, 0.f, 0.f};

  // staging: 512 chunks of 16B (64 rows x 128B); 2 chunks/thread
  int c0 = t * 2, c1 = c0 + 1;
  int kr0 = c0 >> 3, ko0 = (c0 & 7) * 8;
  int kr1 = c1 >> 3, ko1 = (c1 & 7) * 8;

  // prev prefetch registers (one k-tile ahead)
  float4 pv[4];
#pragma unroll
  for (int r4 = 0; r4 < 4; ++r4) {
    int row = r4 * 4 + quad;
    pv[r4] = *(const float4*)(Pvp + (size_t)(qbase + w * 16 + row) * S_ + l16 * 4);
  }

  { // prologue: stage tile 0 into buf 0
    uint4 ka0 = *(const uint4*)(Kp + (size_t)kr0 * K3D_ + ko0);
    uint4 ka1 = *(const uint4*)(Kp + (size_t)kr1 * K3D_ + ko1);
    uint4 va0 = *(const uint4*)(Vtp + (size_t)kr0 * S_ + ko0);
    uint4 va1 = *(const uint4*)(Vtp + (size_t)kr1 * S_ + ko1);
    *(uint4*)(&KsB[0][kr0 * 72 + ko0]) = ka0;
    *(uint4*)(&KsB[0][kr1 * 72 + ko1]) = ka1;
    *(uint4*)(&VsB[0][kr0 * 72 + ko0]) = va0;
    *(uint4*)(&VsB[0][kr1 * 72 + ko1]) = va1;
  }
  __syncthreads();

  for (int it = 0; it < 32; ++it) {
    int cur = it & 1;
    int kb = it * 64;

    // issue next tile's K/V global loads early (latency hides under compute)
    uint4 ka0, ka1, va0, va1;
    if (it < 31) {
      int kn = kb + 64;
      ka0 = *(const uint4*)(Kp + (size_t)(kn + kr0) * K3D_ + ko0);
      ka1 = *(const uint4*)(Kp + (size_t)(kn + kr1) * K3D_ + ko1);
      va0 = *(const uint4*)(Vtp + (size_t)kr0 * S_ + kn + ko0);
      va1 = *(const uint4*)(Vtp + (size_t)kr1 * S_ + kn + ko1);
    }

    const u16* Ks = KsB[cur];
    const u16* Vs = VsB[cur];

    // ---- S = Q @ K^T ----
    f32x4 sa[4];
#pragma unroll
    for (int i = 0; i < 4; ++i) sa[i] = (f32x4){0.f, 0.f, 0.f, 0.f};
#pragma unroll
    for (int kc = 0; kc < 2; ++kc) {
      bf16x8 a = kc ? qf1 : qf0;
#pragma unroll
      for (int nt = 0; nt < 4; ++nt) {
        bf16x8 bk = *(const bf16x8*)(&Ks[(nt * 16 + l16) * 72 + kc * 32 + quad * 8]);
        sa[nt] = __builtin_amdgcn_mfma_f32_16x16x32_bf16(a, bk, sa[nt], 0, 0, 0);
      }
    }

    // ---- fragment -> row-major LDS (scale folded) ----
#pragma unroll
    for (int nt = 0; nt < 4; ++nt)
#pragma unroll
      for (int r = 0; r < 4; ++r)
        Es[w][(quad * 4 + r) * 68 + nt * 16 + l16] = sa[nt][r] * 0.125f;
    asm volatile("" ::: "memory");

    // ---- pass A: e = S + prev(prefetched); coalesced energy write; max ----
    float4 ek[4];
    float mt[4];
#pragma unroll
    for (int r4 = 0; r4 < 4; ++r4) {
      int row = r4 * 4 + quad;
      float4 e4 = *(const float4*)(&Es[w][row * 68 + l16 * 4]);
      size_t goff = (size_t)(qbase + w * 16 + row) * S_ + kb + l16 * 4;
      float4 p4 = pv[r4];
      e4.x += p4.x; e4.y += p4.y; e4.z += p4.z; e4.w += p4.w;
      *(float4*)(Ep + goff) = e4;
      ek[r4] = e4;
      mt[r4] = fmaxf(fmaxf(e4.x, e4.y), fmaxf(e4.z, e4.w));
    }
    // issue next tile's prev loads now; used mid-next-iteration (~full tile
    // of compute to hide HBM latency)
    if (it < 31) {
#pragma unroll
      for (int r4 = 0; r4 < 4; ++r4) {
        int row = r4 * 4 + quad;
        pv[r4] = *(const float4*)(Pvp + (size_t)(qbase + w * 16 + row) * S_ + kb + 64 + l16 * 4);
      }
    }
#pragma unroll
    for (int r4 = 0; r4 < 4; ++r4)
#pragma unroll
      for (int off = 1; off < 16; off <<= 1)
        mt[r4] = fmaxf(mt[r4], __shfl_xor(mt[r4], off, 16));
    if (l16 == 0) {
#pragma unroll
      for (int r4 = 0; r4 < 4; ++r4) {
        int row = r4 * 4 + quad;
        float mo = m_s[w][row];
        float mn = fmaxf(mo, mt[r4]);
        r_s[w][row] = __expf(mo - mn);
        m_s[w][row] = mn;
      }
    }
    asm volatile("" ::: "memory");

    // ---- pass B: P = exp(e - m_new) -> Pt(bf16); l update; O rescale ----
    float ls[4];
#pragma unroll
    for (int r4 = 0; r4 < 4; ++r4) {
      int row = r4 * 4 + quad;
      float mrow = m_s[w][row];
      float4 e4 = ek[r4];
      float p0 = __expf(e4.x - mrow), p1 = __expf(e4.y - mrow);
      float p2 = __expf(e4.z - mrow), p3 = __expf(e4.w - mrow);
      ls[r4] = (p0 + p1) + (p2 + p3);
      u16 pb[4] = {f2b(p0), f2b(p1), f2b(p2), f2b(p3)};
      *(uint2*)(&Pt[w][row * 72 + l16 * 4]) = *(uint2*)pb;
    }
#pragma unroll
    for (int r4 = 0; r4 < 4; ++r4)
#pragma unroll
      for (int off = 1; off < 16; off <<= 1)
        ls[r4] += __shfl_xor(ls[r4], off, 16);
    if (l16 == 0) {
#pragma unroll
      for (int r4 = 0; r4 < 4; ++r4) {
        int row = r4 * 4 + quad;
        l_s[w][row] = l_s[w][row] * r_s[w][row] + ls[r4];
      }
    }
#pragma unroll
    for (int rr = 0; rr < 4; ++rr) {
      float rf = r_s[w][quad * 4 + rr];
#pragma unroll
      for (int nt = 0; nt < 4; ++nt) oa[nt][rr] *= rf;
    }
    asm volatile("" ::: "memory");

    // ---- O += P @ V ----
#pragma unroll
    for (int kc = 0; kc < 2; ++kc) {
      bf16x8 a = *(const bf16x8*)(&Pt[w][l16 * 72 + kc * 32 + quad * 8]);
#pragma unroll
      for (int nt = 0; nt < 4; ++nt) {
        bf16x8 bv = *(const bf16x8*)(&Vs[(nt * 16 + l16) * 72 + kc * 32 + quad * 8]);
        oa[nt] = __builtin_amdgcn_mfma_f32_16x16x32_bf16(a, bv, oa[nt], 0, 0, 0);
      }
    }

    // ---- write-late staging into the other buffer; single barrier ----
    if (it < 31) {
      int nxt = cur ^ 1;
      *(uint4*)(&KsB[nxt][kr0 * 72 + ko0]) = ka0;
      *(uint4*)(&KsB[nxt][kr1 * 72 + ko1]) = ka1;
      *(uint4*)(&VsB[nxt][kr0 * 72 + ko0]) = va0;
      *(uint4*)(&VsB[nxt][kr1 * 72 + ko1]) = va1;
      __syncthreads();
    }
  }

  asm volatile("" ::: "memory");
  // epilogue: O / l -> ctx bf16
  float il[4];
#pragma unroll
  for (int rr = 0; rr < 4; ++rr) il[rr] = 1.f / l_s[w][quad * 4 + rr];
#pragma unroll
  for (int nt = 0; nt < 4; ++nt) {
    int col = h * DH_ + nt * 16 + l16;
#pragma unroll
    for (int rr = 0; rr < 4; ++rr) {
      size_t row = (size_t)b * S_ + qbase + w * 16 + quad * 4 + rr;
      ctx[row * D_ + col] = f2b(oa[nt][rr] * il[rr]);
    }
  }
}

// ---------------------------------------------------------------------------
// LayerNorm: o = LN(a + r) * g + be. a bf16; r fp32 or bf16; o fp32 or bf16.
// One wave per 512-elem row, 4 rows/WG.
// ---------------------------------------------------------------------------
__global__ __launch_bounds__(256) void ln_kernel(
    const u16* __restrict__ a, const void* __restrict__ rsrc,
    const float* __restrict__ g, const float* __restrict__ be,
    void* __restrict__ o, int r_f32, int o_f32) {
  int row = blockIdx.x * 4 + (threadIdx.x >> 6);
  int lane = threadIdx.x & 63;
  size_t base = (size_t)row * D_ + lane * 8;
  uint4 av = *(const uint4*)(a + base);
  const u16* ap = (const u16*)&av;
  float rv[8];
  if (r_f32) {
    float4 r0 = *(const float4*)((const float*)rsrc + base);
    float4 r1 = *(const float4*)((const float*)rsrc + base + 4);
    rv[0] = r0.x; rv[1] = r0.y; rv[2] = r0.z; rv[3] = r0.w;
    rv[4] = r1.x; rv[5] = r1.y; rv[6] = r1.z; rv[7] = r1.w;
  } else {
    uint4 rr = *(const uint4*)((const u16*)rsrc + base);
    const u16* rp = (const u16*)&rr;
#pragma unroll
    for (int j = 0; j < 8; ++j) rv[j] = b2f(rp[j]);
  }
  float tv[8], s = 0.f, sq = 0.f;
#pragma unroll
  for (int j = 0; j < 8; ++j) {
    float xx = b2f(ap[j]) + rv[j];
    tv[j] = xx; s += xx; sq += xx * xx;
  }
#pragma unroll
  for (int off = 32; off; off >>= 1) {
    s  += __shfl_xor(s, off);
    sq += __shfl_xor(sq, off);
  }
  float mu  = s * (1.f / 512.f);
  float var = fmaxf(sq * (1.f / 512.f) - mu * mu, 0.f);
  float wv  = rsqrtf(var + 1e-5f);
  float4 g0 = *(const float4*)(g + lane * 8);
  float4 g1 = *(const float4*)(g + lane * 8 + 4);
  float4 b0 = *(const float4*)(be + lane * 8);
  float4 b1 = *(const float4*)(be + lane * 8 + 4);
  float gv[8] = {g0.x, g0.y, g0.z, g0.w, g1.x, g1.y, g1.z, g1.w};
  float bv[8] = {b0.x, b0.y, b0.z, b0.w, b1.x, b1.y, b1.z, b1.w};
  if (o_f32) {
    float ov[8];
#pragma unroll
    for (int j = 0; j < 8; ++j) ov[j] = (tv[j] - mu) * wv * gv[j] + bv[j];
    *(float4*)((float*)o + base)     = *(float4*)(ov);
    *(float4*)((float*)o + base + 4) = *(float4*)(ov + 4);
  } else {
    u16 ov[8];
#pragma unroll
    for (int j = 0; j < 8; ++j) ov[j] = f2b((tv[j] - mu) * wv * gv[j] + bv[j]);
    *(uint4*)((u16*)o + base) = *(uint4*)ov;
  }
}

// ---------------------------------------------------------------------------
// Workspace plan (29.5 MiB, lifetime-aliased; u16 element offsets):
//   R0 [8,388,608]: kqv (steps 2-5) ; vt in tail [6,291,456..) (3-4) ;
//                   attn in head [0..2,097,152) (6-7) ; ff whole (8-9)
//   R2 [2,097,152]: ctx (4-6) then f2 (9-10)
//   R3 [2,097,152]: hbuf (7-10)
//   R4 [2,097,152]: xb (1-2) then fc1_wt [0..1,048,576) + fc2_wt [1,048,576..)
//   WA [786,432]:   kqv_wt (->2) then out_wt (->6)
// ---------------------------------------------------------------------------
extern "C" void kernel_launch(void* const* d_in, const int* in_sizes, int n_in,
                              void* d_out, int out_size, void* d_ws, size_t ws_size,
                              hipStream_t stream) {
  const float* x     = (const float*)d_in[0];
  const float* prev  = (const float*)d_in[1];
  const float* kqv_w = (const float*)d_in[2];
  const float* kqv_b = (const float*)d_in[3];
  const float* out_w = (const float*)d_in[4];
  const float* out_b = (const float*)d_in[5];
  const float* fc1_w = (const float*)d_in[6];
  const float* fc1_b = (const float*)d_in[7];
  const float* fc2_w = (const float*)d_in[8];
  const float* fc2_b = (const float*)d_in[9];
  const float* ln1_g = (const float*)d_in[10];
  const float* ln1_b = (const float*)d_in[11];
  const float* ln2_g = (const float*)d_in[12];
  const float* ln2_b = (const float*)d_in[13];

  float* outp   = (float*)d_out;                    // [4096,512] fp32
  float* energy = outp + (size_t)NT_ * D_;          // [16,2048,2048] fp32

  u16* ws = (u16*)d_ws;
  u16* R0 = ws;                       // 8,388,608
  u16* R2 = R0 + (size_t)8388608;     // 2,097,152
  u16* R3 = R2 + (size_t)2097152;     // 2,097,152
  u16* R4 = R3 + (size_t)2097152;     // 2,097,152
  u16* WA = R4 + (size_t)2097152;     // 786,432   (total 15,466,496 u16 = 29.5 MiB)

  u16* kqv    = R0;
  u16* vt     = R0 + (size_t)6291456;
  u16* attn   = R0;
  u16* ff     = R0;
  u16* ctx    = R2;  u16* f2     = R2;
  u16* hbuf   = R3;
  u16* xb     = R4;
  u16* fc1_wt = R4;  u16* fc2_wt = R4 + (size_t)1048576;
  u16* kqv_wt = WA;  u16* out_wt = WA;

  // step 1: xb = bf16(x); kqv_wt
  cvt_kernel<<<(NT_ * D_ / 8 + 255) / 256, 256, 0, stream>>>(x, xb, NT_ * D_ / 8);
  transpose_t32<<<dim3(K3D_ / 32, D_ / 32), 256, 0, stream>>>(kqv_w, kqv_wt, D_, K3D_);

  // step 2: kqv = xb @ kqv_w + b : M=4096 N=1536 K=512
  gemm_glds<128><<<dim3(K3D_ / 128, NT_ / 128, 1), 256, 0, stream>>>(
      xb, kqv_wt, kqv_b, kqv, D_, D_, D_, K3D_, 0);

  // step 1b: remaining weight transposes (xb, kqv_wt now dead)
  transpose_t32<<<dim3(HID_ / 32, D_ / 32), 256, 0, stream>>>(fc1_w, fc1_wt, D_, HID_);
  transpose_t32<<<dim3(D_ / 32, HID_ / 32), 256, 0, stream>>>(fc2_w, fc2_wt, HID_, D_);
  transpose_t32<<<dim3(D_ / 32, D_ / 32), 256, 0, stream>>>(out_w, out_wt, D_, D_);

  // step 3: Vt for PV MFMA
  vt_tiled<<<dim3(S_ / 64, 16), 256, 0, stream>>>(kqv, vt);

  // step 4: fused flash attention: energy out (fp32) + ctx (bf16)
  fused_attn<<<dim3(S_ / 64, 16), 256, 0, stream>>>(kqv, vt, prev, energy, ctx);

  // step 6: attn = ctx @ out_w + b  (bf16, into R0 head); BN=64 -> 256 blocks
  gemm_glds<64><<<dim3(D_ / 64, NT_ / 128, 1), 256, 0, stream>>>(
      ctx, out_wt, out_b, attn, D_, D_, D_, D_, 0);

  // step 7: h = LN1(attn + x)  -> hbuf bf16   (r fp32, o bf16)
  ln_kernel<<<NT_ / 4, 256, 0, stream>>>(attn, x, ln1_g, ln1_b, hbuf, 1, 0);

  // step 8: ff = gelu(h @ fc1_w + b)  (writes all R0; attn/vt dead)
  gemm_glds<128><<<dim3(HID_ / 128, NT_ / 128, 1), 256, 0, stream>>>(
      hbuf, fc1_wt, fc1_b, ff, D_, D_, D_, HID_, 1);

  // step 9: f2 = ff @ fc2_w + b  (writes R2; ctx dead); BN=64 -> 256 blocks
  gemm_glds<64><<<dim3(D_ / 64, NT_ / 128, 1), 256, 0, stream>>>(
      ff, fc2_wt, fc2_b, f2, HID_, HID_, HID_, D_, 0);

  // step 10: out = LN2(f2 + h) -> fp32  (r bf16, o fp32)
  ln_kernel<<<NT_ / 4, 256, 0, stream>>>(f2, hbuf, ln2_g, ln2_b, outp, 0, 1);
}